// Round 2
// baseline (2318.772 us; speedup 1.0000x reference)
//
#include <hip/hip_runtime.h>
#include <hip/hip_bf16.h>
#include <string.h>

// GNN layer, bf16-MFMA restructuring, round 2: bucketed (sorted) edge pass.
//   AB = nf @ [We1_s | We1_d]      [N,512] bf16  (A|B halves per row)
//   Binning: counting-sort edge ids into 64-node buckets by dst (forward
//   visits) and by src (backward visits). Unified formula per visit:
//        H[own] += lrelu(A[other] + B[own] + C[e])
//   edge_bucket (one block = one bucket x one 128-feature half):
//     - per 64-visit chunk: gather ef rows -> MFMA C -> LDS
//     - msg loop: A[other] random gather, B[own] L2-local, C from LDS,
//       accumulate into LDS fp32 H-accum (ds_add_f32 -- ZERO global atomics)
//     - one non-atomic bf16 write of the bucket's H rows at the end
//   red = H @ We2 ; hid = lrelu([nf|red]@Wn1) ; out = hid @ Wn2
// Rationale (round-1 counters): edge kernel pinned at 430us across two very
// different structures with no pipe saturated; WRITE_SIZE == 2E*512B exactly
// => device-scope pk atomics resolve memory-side. Eliminate them.

using f32x4  = __attribute__((ext_vector_type(4))) float;
using bf16x8 = __attribute__((ext_vector_type(8))) short;

#define LROW 72    // staging LDS row pitch in bf16 units (144 B)
#define CROW 132   // C tile LDS pitch in bf16 units (264 B)
#define BSH  6     // bucket = 64 nodes
#define BNODES 64

__device__ __forceinline__ float lrelu(float x) { return x >= 0.f ? x : 0.01f * x; }

__device__ __forceinline__ ushort f2bf(float f) {
    union { float f; unsigned u; } v; v.f = f;
    unsigned u = v.u;
    return (ushort)((u + 0x7fffu + ((u >> 16) & 1u)) >> 16);   // RNE
}
__device__ __forceinline__ float bf2f(ushort u) {
    union { unsigned u; float f; } v; v.u = ((unsigned)u) << 16; return v.f;
}

// out[M,Nw] = cat(X1[M,K1], X2[M,K2]) @ Wt^T   (Wt is [Nw,K] bf16, n-major)
// flags: 1 = lrelu, 2 = bf16 output (else fp32)
__global__ __launch_bounds__(256) void gemm_bf16(
    const ushort* __restrict__ X1, int K1,
    const ushort* __restrict__ X2, int K2,
    const ushort* __restrict__ Wt,
    void* __restrict__ out, int Nw, int Mstore, int flags)
{
    __shared__ ushort Xs[128 * LROW];
    __shared__ ushort Ws[128 * LROW];

    const int K    = K1 + K2;
    const int tid  = threadIdx.x;
    const int lane = tid & 63;
    const int wv   = tid >> 6;
    const int wm   = wv >> 1, wn = wv & 1;
    const int row0 = blockIdx.x * 128;
    const int col0 = blockIdx.y * 128;

    f32x4 acc[4][4] = {};

    for (int k0 = 0; k0 < K; k0 += 64) {
        const ushort* Xsrc; int kloc, ksz;
        if (k0 < K1) { Xsrc = X1; kloc = k0;      ksz = K1; }
        else         { Xsrc = X2; kloc = k0 - K1; ksz = K2; }

        const int r_  = tid >> 3;          // 0..31
        const int kk  = (tid & 7) * 8;     // bf16 offset 0..56
        uint4 xv[4], wvv[4];
        #pragma unroll
        for (int p = 0; p < 4; ++p) {
            int r = p * 32 + r_;
            xv[p]  = *reinterpret_cast<const uint4*>(Xsrc + (size_t)(row0 + r) * ksz + kloc + kk);
            wvv[p] = *reinterpret_cast<const uint4*>(Wt   + (size_t)(col0 + r) * K   + k0   + kk);
        }
        __syncthreads();
        #pragma unroll
        for (int p = 0; p < 4; ++p) {
            int r = p * 32 + r_;
            *reinterpret_cast<uint4*>(&Xs[r * LROW + kk]) = xv[p];
            *reinterpret_cast<uint4*>(&Ws[r * LROW + kk]) = wvv[p];
        }
        __syncthreads();

        #pragma unroll
        for (int ks = 0; ks < 2; ++ks) {
            bf16x8 af[4], bfr[4];
            #pragma unroll
            for (int i = 0; i < 4; ++i) {
                int mrow = wm * 64 + i * 16 + (lane & 15);
                af[i]  = *reinterpret_cast<const bf16x8*>(&Xs[mrow * LROW + ks * 32 + (lane >> 4) * 8]);
                int ncol = wn * 64 + i * 16 + (lane & 15);
                bfr[i] = *reinterpret_cast<const bf16x8*>(&Ws[ncol * LROW + ks * 32 + (lane >> 4) * 8]);
            }
            #pragma unroll
            for (int i = 0; i < 4; ++i)
                #pragma unroll
                for (int j = 0; j < 4; ++j)
                    acc[i][j] = __builtin_amdgcn_mfma_f32_16x16x32_bf16(af[i], bfr[j], acc[i][j], 0, 0, 0);
        }
    }

    // C/D layout: col = lane&15, row = (lane>>4)*4 + reg
    #pragma unroll
    for (int i = 0; i < 4; ++i) {
        int gr0 = row0 + wm * 64 + i * 16 + ((lane >> 4) << 2);
        #pragma unroll
        for (int j = 0; j < 4; ++j) {
            int gc = col0 + wn * 64 + j * 16 + (lane & 15);
            #pragma unroll
            for (int r = 0; r < 4; ++r) {
                int gr = gr0 + r;
                if (gr >= Mstore) continue;
                float v = acc[i][j][r];
                if (flags & 1) v = lrelu(v);
                if (flags & 2) ((ushort*)out)[(size_t)gr * Nw + gc] = f2bf(v);
                else           ((float*) out)[(size_t)gr * Nw + gc] = v;
            }
        }
    }
}

// ---- binning: counting sort of edges into 64-node buckets ----
// cnt[0..NB)   = per-bucket count by dst (forward visits)
// cnt[NB..2NB) = per-bucket count by src (backward visits)
__global__ __launch_bounds__(256) void ebin_count(
    const int* __restrict__ src, const int* __restrict__ dst,
    int* __restrict__ cnt, int E, int NB)
{
    int i = blockIdx.x * 256 + threadIdx.x;
    if (i >= E) return;
    atomicAdd(&cnt[dst[i] >> BSH], 1);
    atomicAdd(&cnt[NB + (src[i] >> BSH)], 1);
}

// exclusive scan over cnt[0..n) -> base[0..n], cur = copy of base. 1 block.
__global__ __launch_bounds__(256) void escan(
    const int* __restrict__ cnt, int* __restrict__ base, int* __restrict__ cur, int n)
{
    __shared__ int ps[256];
    const int t = threadIdx.x;
    const int per = (n + 255) / 256;
    int s = 0;
    for (int i = 0; i < per; ++i) { int idx = t * per + i; if (idx < n) s += cnt[idx]; }
    ps[t] = s;
    __syncthreads();
    for (int off = 1; off < 256; off <<= 1) {
        int u = (t >= off) ? ps[t - off] : 0;
        __syncthreads();
        ps[t] += u;
        __syncthreads();
    }
    int run = ps[t] - s;                       // exclusive base of this chunk
    for (int i = 0; i < per; ++i) {
        int idx = t * per + i;
        if (idx < n) { base[idx] = run; cur[idx] = run; run += cnt[idx]; }
    }
    if (t == 255) base[n] = run;               // sentinel = 2E
}

__global__ __launch_bounds__(256) void escatter(
    const int* __restrict__ src, const int* __restrict__ dst,
    int* __restrict__ cur, int* __restrict__ perm, int E, int NB)
{
    int i = blockIdx.x * 256 + threadIdx.x;
    if (i >= E) return;
    int p1 = atomicAdd(&cur[dst[i] >> BSH], 1);       perm[p1] = i;
    int p2 = atomicAdd(&cur[NB + (src[i] >> BSH)], 1); perm[p2] = i;
}

// ---- bucketed edge pass: zero global atomics ----
// grid = (NB, 2 feature halves), 512 threads (8 waves).
// LDS: Wet-half 18.4K + Cs 16.9K + Hs(fp32) 32.8K + ids ~0.8K = 68.9 KB
//   -> 2 blocks/CU.
__global__ __launch_bounds__(512) void edge_bucket(
    const ushort* __restrict__ efb,   // [Ep,64] bf16
    const ushort* __restrict__ Wet,   // [256,64] bf16, n-major
    const ushort* __restrict__ AB,    // [Np,512] bf16: row = [A(256) | B(256)]
    const int* __restrict__ src, const int* __restrict__ dst,
    const int* __restrict__ perm, const int* __restrict__ base,
    ushort* __restrict__ H,           // [Np,256] bf16 (written once, no atomics)
    int NB)
{
    __shared__ ushort Ws[128 * LROW];          // Wet half, persistent
    __shared__ ushort Cs[BNODES * CROW];       // C chunk (64 visits x 128 cols)
    __shared__ float  Hs[BNODES * 128];        // fp32 accumulator, 64 nodes x 128 cols
    __shared__ int eids[64], ownl[64], othn[64];

    const int tid   = threadIdx.x;
    const int lane  = tid & 63;
    const int wv    = tid >> 6;                // 0..7
    const int wm    = wv >> 1, wn = wv & 1;
    const int b     = blockIdx.x;
    const int col0  = blockIdx.y * 128;
    const int node0 = b << BSH;

    #pragma unroll
    for (int i = 0; i < 16; ++i) Hs[tid + i * 512] = 0.f;

    {   // stage Wet half (output features col0..col0+127, K=64)
        const int r_ = tid >> 3;               // 0..63
        const int kk = (tid & 7) * 8;
        #pragma unroll
        for (int p = 0; p < 2; ++p) {
            int r = p * 64 + r_;
            *reinterpret_cast<uint4*>(&Ws[r * LROW + kk]) =
                *reinterpret_cast<const uint4*>(Wet + (size_t)(col0 + r) * 64 + kk);
        }
    }

    const int d0 = base[b],      d1 = base[b + 1];
    const int s0 = base[NB + b], s1 = base[NB + b + 1];
    const int cd = d1 - d0;
    const int nv = cd + (s1 - s0);

    for (int v0 = 0; v0 < nv; v0 += 64) {
        __syncthreads();   // prev chunk's Cs/eids reads done; Ws/Hs ready (iter 0)
        if (tid < 64) {
            int vid = v0 + tid;
            int e = 0, own = -1, oth = 0;
            if (vid < nv) {
                if (vid < cd) { e = perm[d0 + vid];      own = dst[e]; oth = src[e]; }
                else          { e = perm[s0 + vid - cd]; own = src[e]; oth = dst[e]; }
            }
            eids[tid] = e;
            ownl[tid] = (own < 0) ? -1 : own - node0;
            othn[tid] = oth;
        }
        __syncthreads();

        // C chunk: [64 visits x 128 cols] = ef[eids] @ Wet-half (K=64)
        // A-fragments gathered straight from global (16B per lane per frag).
        f32x4 acc[4] = {};
        #pragma unroll
        for (int ks = 0; ks < 2; ++ks) {
            int mrow = wm * 16 + (lane & 15);
            int e = eids[mrow];
            bf16x8 af = *reinterpret_cast<const bf16x8*>(
                efb + (size_t)e * 64 + ks * 32 + (lane >> 4) * 8);
            #pragma unroll
            for (int j = 0; j < 4; ++j) {
                int ncol = wn * 64 + j * 16 + (lane & 15);
                bf16x8 bf = *reinterpret_cast<const bf16x8*>(
                    &Ws[ncol * LROW + ks * 32 + (lane >> 4) * 8]);
                acc[j] = __builtin_amdgcn_mfma_f32_16x16x32_bf16(af, bf, acc[j], 0, 0, 0);
            }
        }
        {   // acc -> Cs (C/D layout: col = lane&15, row = (lane>>4)*4 + reg)
            int er0 = wm * 16 + ((lane >> 4) << 2);
            #pragma unroll
            for (int j = 0; j < 4; ++j) {
                int fc = wn * 64 + j * 16 + (lane & 15);
                #pragma unroll
                for (int r = 0; r < 4; ++r)
                    Cs[(er0 + r) * CROW + fc] = f2bf(acc[j][r]);
            }
        }
        __syncthreads();

        // msg loop: wave wv handles visits v = p*8+wv; lane = feature pair.
        // Branchless padding: pad visits get weight 0, accumulate 0 to row 63.
        const int jj = lane * 2;
        #pragma unroll
        for (int p = 0; p < 8; ++p) {
            int v = p * 8 + wv;
            int ol = ownl[v];
            float w = (ol >= 0) ? 1.f : 0.f;
            ol &= (BNODES - 1);
            int oth = othn[v];
            ushort2 av = *(const ushort2*)(AB + (size_t)oth * 512 + col0 + jj);
            ushort2 bv = *(const ushort2*)(AB + (size_t)(node0 + ol) * 512 + 256 + col0 + jj);
            ushort2 cv = *(const ushort2*)(&Cs[v * CROW + jj]);
            float m0 = lrelu(bf2f(av.x) + bf2f(bv.x) + bf2f(cv.x));
            float m1 = lrelu(bf2f(av.y) + bf2f(bv.y) + bf2f(cv.y));
            atomicAdd(&Hs[ol * 128 + jj],     w * m0);
            atomicAdd(&Hs[ol * 128 + jj + 1], w * m1);
        }
    }
    __syncthreads();

    {   // write bucket's H rows once (non-atomic, coalesced per 4-thread group)
        int row = tid >> 3, seg = tid & 7;     // 64 rows x 8 segs x 16 cols
        ushort* dp = H + (size_t)(node0 + row) * 256 + col0 + seg * 16;
        #pragma unroll
        for (int q = 0; q < 8; ++q) {
            ushort2 o;
            o.x = f2bf(Hs[row * 128 + seg * 16 + q * 2]);
            o.y = f2bf(Hs[row * 128 + seg * 16 + q * 2 + 1]);
            *(ushort2*)(dp + q * 2) = o;
        }
    }
}

// float -> bf16 with zero padding; n_real, n_pad multiples of 4
__global__ __launch_bounds__(256) void cvt_pad(
    const float* __restrict__ x, ushort* __restrict__ y, size_t n_real, size_t n_pad)
{
    size_t i = ((size_t)blockIdx.x * 256 + threadIdx.x) * 4;
    if (i >= n_pad) return;
    ushort4 o;
    if (i < n_real) {
        float4 v = *(const float4*)(x + i);
        o.x = f2bf(v.x); o.y = f2bf(v.y); o.z = f2bf(v.z); o.w = f2bf(v.w);
    } else { o.x = 0; o.y = 0; o.z = 0; o.w = 0; }
    *(ushort4*)(y + i) = o;
}

// transpose + convert all weights to bf16 [N,K] layouts
__global__ __launch_bounds__(256) void wcvt(
    const float* __restrict__ We1, const float* __restrict__ We2,
    const float* __restrict__ Wn1, const float* __restrict__ Wn2,
    ushort* __restrict__ Wabt, ushort* __restrict__ Wet, ushort* __restrict__ We2t,
    ushort* __restrict__ Wn1t, ushort* __restrict__ Wn2t)
{
    int idx = blockIdx.x * 256 + threadIdx.x;
    switch (blockIdx.y) {
    case 0: if (idx < 256*128) { int n = idx >> 7, k = idx & 127; Wabt[idx]            = f2bf(We1[k * 256 + n]); } break;
    case 1: if (idx < 256*128) { int n = idx >> 7, k = idx & 127; Wabt[32768 + idx]    = f2bf(We1[(128 + k) * 256 + n]); } break;
    case 2: if (idx < 256*64)  { int n = idx >> 6, k = idx & 63;  Wet[idx]             = f2bf(We1[(256 + k) * 256 + n]); } break;
    case 3: if (idx < 128*256) { int n = idx >> 8, k = idx & 255; We2t[idx]            = f2bf(We2[k * 128 + n]); } break;
    case 4: if (idx < 256*256) { int n = idx >> 8, k = idx & 255; Wn1t[idx]            = f2bf(Wn1[k * 256 + n]); } break;
    case 5: if (idx < 128*256) { int n = idx >> 8, k = idx & 255; Wn2t[idx]            = f2bf(Wn2[k * 128 + n]); } break;
    }
}

extern "C" void kernel_launch(void* const* d_in, const int* in_sizes, int n_in,
                              void* d_out, int out_size, void* d_ws, size_t ws_size,
                              hipStream_t stream) {
    const float* nf  = (const float*)d_in[0];
    const float* ef  = (const float*)d_in[1];
    const int*   src = (const int*)d_in[2];
    const int*   dst = (const int*)d_in[3];
    const float* We1 = (const float*)d_in[4];
    const float* We2 = (const float*)d_in[5];
    const float* Wn1 = (const float*)d_in[6];
    const float* Wn2 = (const float*)d_in[7];
    float* out = (float*)d_out;

    const int  N  = in_sizes[0] / 128;            // 100000
    const int  E  = in_sizes[2];                  // 500000
    const int  Np = (N + 127) & ~127;             // 100096
    const long Ep = ((long)E + 127) & ~127L;      // 500096
    const int  NB = Np >> BSH;                    // 1564 buckets of 64 nodes

    char* p = (char*)d_ws;
    auto alloc = [&](size_t bytes) { char* r = p; p += (bytes + 255) & ~(size_t)255; return r; };
    ushort* AB    = (ushort*)alloc((size_t)Np * 512 * 2);
    ushort* H     = (ushort*)alloc((size_t)Np * 256 * 2);
    ushort* nfb   = (ushort*)alloc((size_t)Np * 128 * 2);
    ushort* efb   = (ushort*)alloc((size_t)Ep * 64 * 2);
    ushort* Wabt  = (ushort*)alloc(65536 * 2);
    ushort* Wet   = (ushort*)alloc(16384 * 2);
    ushort* We2t  = (ushort*)alloc(32768 * 2);
    ushort* Wn1t  = (ushort*)alloc(65536 * 2);
    ushort* Wn2t  = (ushort*)alloc(32768 * 2);
    int*    cnt   = (int*)alloc((size_t)(2 * NB) * 4);
    int*    basep = (int*)alloc((size_t)(2 * NB + 1) * 4);
    int*    cur   = (int*)alloc((size_t)(2 * NB) * 4);
    int*    perm  = (int*)alloc((size_t)2 * E * 4);
    ushort* red = AB;                              // alias: AB dead after edge pass
    ushort* hid = AB + (size_t)Np * 128;

    dim3 blk(256);
    const unsigned egrid = (unsigned)((E + 255) / 256);

    wcvt<<<dim3(256, 6), blk, 0, stream>>>(We1, We2, Wn1, Wn2, Wabt, Wet, We2t, Wn1t, Wn2t);
    cvt_pad<<<dim3((unsigned)((size_t)Np * 128 / 1024)), blk, 0, stream>>>(nf, nfb, (size_t)N * 128, (size_t)Np * 128);
    cvt_pad<<<dim3((unsigned)((size_t)Ep * 64 / 1024)), blk, 0, stream>>>(ef, efb, (size_t)E * 64, (size_t)Ep * 64);

    // binning (counting sort into 64-node buckets, by dst then by src)
    hipMemsetAsync(cnt, 0, (size_t)(2 * NB) * 4, stream);
    ebin_count<<<dim3(egrid), blk, 0, stream>>>(src, dst, cnt, E, NB);
    escan<<<dim3(1), blk, 0, stream>>>(cnt, basep, cur, 2 * NB);
    escatter<<<dim3(egrid), blk, 0, stream>>>(src, dst, cur, perm, E, NB);

    // AB = nf @ [We1_s | We1_d]
    gemm_bf16<<<dim3(Np / 128, 4), blk, 0, stream>>>(nfb, 128, nullptr, 0, Wabt, AB, 512, Np, 2);

    // bucketed edge pass: fused C-GEMM + LDS accumulation, no global atomics,
    // H written exactly once (pad-node buckets write zeros -> no memset)
    edge_bucket<<<dim3(NB, 2), dim3(512), 0, stream>>>(
        efb, Wet, AB, src, dst, perm, basep, H, NB);

    // red = H @ We2
    gemm_bf16<<<dim3(Np / 128, 1), blk, 0, stream>>>(H, 256, nullptr, 0, We2t, red, 128, Np, 2);
    // hid = lrelu([nf|red] @ Wn1)
    gemm_bf16<<<dim3(Np / 128, 2), blk, 0, stream>>>(nfb, 128, red, 128, Wn1t, hid, 256, Np, 2 | 1);
    // out = hid @ Wn2  (fp32, guarded stores)
    gemm_bf16<<<dim3(Np / 128, 1), blk, 0, stream>>>(hid, 256, nullptr, 0, Wn2t, (void*)out, 128, N, 0);
}

// Round 3
// 830.000 us; speedup vs baseline: 2.7937x; 2.7937x over previous
//
#include <hip/hip_runtime.h>
#include <hip/hip_bf16.h>
#include <string.h>

// GNN layer, round 3: revert edge path to round-1 edge_fused (known 430us,
// atomic-rate-capped at ~1 pk-atomic/clk/L2-slice); attack the 532us non-edge
// tail instead:
//   gemm_ab:   AB = nf @ [We1_s|We1_d]. X staged ONCE, 4 col-blocks looped
//              in-kernel, W fragments loaded straight from global (L2-hit).
//   edge_fused: C = ef@We1_e MFMA'd into LDS, messages + pk_add_bf16 atomics
//              (unchanged from round 1).
//   mlp_fused: H -> red -> hid -> out in ONE kernel. red/hid live only in
//              LDS overlays; weights fragment-loaded from L2; nf tile
//              register-prefetched during phase 1.
// Round-2 lesson encoded: no concurrent LDS atomics on sorted keys; the only
// accumulators here are per-lane registers or the (unsorted) global atomics.

using f32x4  = __attribute__((ext_vector_type(4))) float;
using bf16x8 = __attribute__((ext_vector_type(8))) short;

#define LROW 72    // edge_fused staging pitch (bf16 units)
#define CROW 132   // edge_fused C-tile pitch
#define P128 132   // K=128 LDS tile pitch (264 B)
#define P256 264   // K=256 LDS tile pitch (528 B)

__device__ __forceinline__ float lrelu(float x) { return x >= 0.f ? x : 0.01f * x; }

__device__ __forceinline__ ushort f2bf(float f) {
    union { float f; unsigned u; } v; v.f = f;
    unsigned u = v.u;
    return (ushort)((u + 0x7fffu + ((u >> 16) & 1u)) >> 16);   // RNE
}
__device__ __forceinline__ float bf2f(ushort u) {
    union { unsigned u; float f; } v; v.u = ((unsigned)u) << 16; return v.f;
}

__device__ __forceinline__ void atomic_pk_add_bf16(void* addr, unsigned val) {
    asm volatile("global_atomic_pk_add_bf16 %0, %1, off" : : "v"(addr), "v"(val) : "memory");
}

// ---------------- AB GEMM: X staged once, W frags from global ----------------
// AB[Np,512] = nfb[Np,128] @ Wabt^T   (Wabt [512,128] n-major, L2-resident)
__global__ __launch_bounds__(256) void gemm_ab(
    const ushort* __restrict__ X,     // [Np,128] bf16
    const ushort* __restrict__ Wt,    // [512,128] bf16
    ushort* __restrict__ out)         // [Np,512] bf16
{
    __shared__ ushort Xs[128 * P128];
    const int tid  = threadIdx.x;
    const int lane = tid & 63;
    const int wv   = tid >> 6;
    const int wm   = wv >> 1, wn = wv & 1;
    const int row0 = blockIdx.x * 128;

    // stage X tile (128 x 128 bf16): 2048 uint4, 8 per thread, coalesced
    #pragma unroll
    for (int q = 0; q < 8; ++q) {
        int idx = q * 256 + tid;
        int r = idx >> 4, c = idx & 15;
        *reinterpret_cast<uint4*>(&Xs[r * P128 + c * 8]) =
            *reinterpret_cast<const uint4*>(X + (size_t)(row0 + r) * 128 + c * 8);
    }
    __syncthreads();

    const int g8 = (lane >> 4) * 8;
    for (int cb = 0; cb < 4; ++cb) {
        f32x4 acc[4][4] = {};
        #pragma unroll
        for (int ks = 0; ks < 4; ++ks) {
            bf16x8 af[4], bf[4];
            #pragma unroll
            for (int i = 0; i < 4; ++i) {
                int mrow = wm * 64 + i * 16 + (lane & 15);
                af[i] = *reinterpret_cast<const bf16x8*>(&Xs[mrow * P128 + ks * 32 + g8]);
                int nc = cb * 128 + wn * 64 + i * 16 + (lane & 15);
                bf[i] = *reinterpret_cast<const bf16x8*>(Wt + (size_t)nc * 128 + ks * 32 + g8);
            }
            #pragma unroll
            for (int i = 0; i < 4; ++i)
                #pragma unroll
                for (int j = 0; j < 4; ++j)
                    acc[i][j] = __builtin_amdgcn_mfma_f32_16x16x32_bf16(af[i], bf[j], acc[i][j], 0, 0, 0);
        }
        // C/D layout: col = lane&15, row = (lane>>4)*4 + reg
        #pragma unroll
        for (int i = 0; i < 4; ++i) {
            int gr0 = row0 + wm * 64 + i * 16 + ((lane >> 4) << 2);
            #pragma unroll
            for (int j = 0; j < 4; ++j) {
                int gc = cb * 128 + wn * 64 + j * 16 + (lane & 15);
                #pragma unroll
                for (int r = 0; r < 4; ++r)
                    out[(size_t)(gr0 + r) * 512 + gc] = f2bf(acc[i][j][r]);
            }
        }
    }
}

// ---------------- fused edge pass (verbatim round 1, 430us known-good) ------
__global__ __launch_bounds__(256) void edge_fused(
    const ushort* __restrict__ efb,   // [Ep,64] bf16 (zero-padded)
    const ushort* __restrict__ Wet,   // [256,64] bf16, n-major
    const ushort* __restrict__ AB,    // [Np,512] bf16: row = [A(256) | B(256)]
    const int* __restrict__ src, const int* __restrict__ dst,
    ushort* __restrict__ H,           // [Np,256] bf16 accumulator
    int E)
{
    __shared__ ushort lds[128 * LROW * 2];   // staging, then aliased as C tile
    __shared__ int sd[256];                  // src[0..127] | dst[0..127]

    const int tid  = threadIdx.x;
    const int lane = tid & 63;
    const int wv   = tid >> 6;
    const int wm   = wv >> 1, wn = wv & 1;
    const int bid  = blockIdx.x;
    const int eb   = (bid >> 1) * 128;       // edge block base
    const int col0 = (bid & 1) * 128;        // feature half

    ushort* Xs = lds;                        // ef tile [128][LROW]
    ushort* Ws = lds + 128 * LROW;           // Wet half [128][LROW]

    const int r_ = tid >> 3;                 // 0..31
    const int kk = (tid & 7) * 8;            // bf16 offset 0..56
    uint4 xv[4], wvv[4];
    #pragma unroll
    for (int p = 0; p < 4; ++p) {
        int r = p * 32 + r_;
        xv[p]  = *reinterpret_cast<const uint4*>(efb + (size_t)(eb + r) * 64 + kk);
        wvv[p] = *reinterpret_cast<const uint4*>(Wet + (size_t)(col0 + r) * 64 + kk);
    }
    if (tid < 128) sd[tid] = (eb + tid < E)         ? src[eb + tid]         : -1;
    else           sd[tid] = (eb + (tid - 128) < E) ? dst[eb + (tid - 128)] : -1;
    #pragma unroll
    for (int p = 0; p < 4; ++p) {
        int r = p * 32 + r_;
        *reinterpret_cast<uint4*>(&Xs[r * LROW + kk]) = xv[p];
        *reinterpret_cast<uint4*>(&Ws[r * LROW + kk]) = wvv[p];
    }
    __syncthreads();

    f32x4 acc[4][4] = {};
    #pragma unroll
    for (int ks = 0; ks < 2; ++ks) {
        bf16x8 af[4], bfr[4];
        #pragma unroll
        for (int i = 0; i < 4; ++i) {
            int mrow = wm * 64 + i * 16 + (lane & 15);
            af[i]  = *reinterpret_cast<const bf16x8*>(&Xs[mrow * LROW + ks * 32 + (lane >> 4) * 8]);
            int ncol = wn * 64 + i * 16 + (lane & 15);
            bfr[i] = *reinterpret_cast<const bf16x8*>(&Ws[ncol * LROW + ks * 32 + (lane >> 4) * 8]);
        }
        #pragma unroll
        for (int i = 0; i < 4; ++i)
            #pragma unroll
            for (int j = 0; j < 4; ++j)
                acc[i][j] = __builtin_amdgcn_mfma_f32_16x16x32_bf16(af[i], bfr[j], acc[i][j], 0, 0, 0);
    }
    __syncthreads();           // staging reads done -> alias LDS as C tile

    ushort* Cs = lds;
    #pragma unroll
    for (int i = 0; i < 4; ++i) {
        int er0 = wm * 64 + i * 16 + ((lane >> 4) << 2);
        #pragma unroll
        for (int j = 0; j < 4; ++j) {
            int fc = wn * 64 + j * 16 + (lane & 15);
            #pragma unroll
            for (int r = 0; r < 4; ++r)
                Cs[(er0 + r) * CROW + fc] = f2bf(acc[i][j][r]);
        }
    }
    __syncthreads();

    const int jj = lane * 2;                 // feature pair within this half
    const ushort* ABj = AB + col0 + jj;
    ushort* Hj = H + col0 + jj;
    for (int p = 0; p < 32; ++p) {
        int ee = p * 4 + wv;
        int s = sd[ee], d = sd[128 + ee];
        if (s < 0) continue;                 // wave-uniform (pad edges)
        ushort2 cv = *(const ushort2*)(&Cs[ee * CROW + jj]);
        ushort2 as = *(const ushort2*)(ABj + (size_t)s * 512);
        ushort2 bs = *(const ushort2*)(ABj + (size_t)s * 512 + 256);
        ushort2 ad = *(const ushort2*)(ABj + (size_t)d * 512);
        ushort2 bd = *(const ushort2*)(ABj + (size_t)d * 512 + 256);
        float c0 = bf2f(cv.x), c1 = bf2f(cv.y);
        ushort2 mf, mb;
        mf.x = f2bf(lrelu(bf2f(as.x) + bf2f(bd.x) + c0));
        mf.y = f2bf(lrelu(bf2f(as.y) + bf2f(bd.y) + c1));
        mb.x = f2bf(lrelu(bf2f(ad.x) + bf2f(bs.x) + c0));
        mb.y = f2bf(lrelu(bf2f(ad.y) + bf2f(bs.y) + c1));
        unsigned uf, ub;
        memcpy(&uf, &mf, 4); memcpy(&ub, &mb, 4);
        atomic_pk_add_bf16(Hj + (size_t)d * 256, uf);
        atomic_pk_add_bf16(Hj + (size_t)s * 256, ub);
    }
}

// ---------------- fused MLP tail: H -> red -> hid -> out ----------------
// Per 128-row tile. LDS overlays (67.6 KB total, 2 blocks/CU):
//   phase 1: Hs[128][P256]           red = Hs @ We2t       (K=256)
//   phase 2: Rs[128][P128]+Ns[128][P128]  hid = lrelu([Ns|Rs] @ Wn1t)
//   phase 3: Hid[128][P256]          out = Hid @ Wn2t      (K=256)
// Weights fragment-loaded from global (L2-resident, <=128KB each).
__global__ __launch_bounds__(256) void mlp_fused(
    const ushort* __restrict__ H,     // [Np,256] bf16
    const ushort* __restrict__ nfb,   // [Np,128] bf16
    const ushort* __restrict__ We2t,  // [128,256] bf16 n-major
    const ushort* __restrict__ Wn1t,  // [256,256] bf16 n-major
    const ushort* __restrict__ Wn2t,  // [128,256] bf16 n-major
    float* __restrict__ out, int Nreal)
{
    __shared__ ushort lds[128 * P256];
    ushort* Hs  = lds;
    ushort* Rs  = lds;                  // overlay after phase 1
    ushort* Ns  = lds + 128 * P128;
    ushort* Hid = lds;                  // overlay after phase 2

    const int tid  = threadIdx.x;
    const int lane = tid & 63;
    const int wv   = tid >> 6;
    const int wm   = wv >> 1, wn = wv & 1;
    const int row0 = blockIdx.x * 128;
    const int g8   = (lane >> 4) * 8;

    // prefetch nf tile into registers (consumed after phase 1)
    uint4 npre[8];
    #pragma unroll
    for (int q = 0; q < 8; ++q) {
        int idx = q * 256 + tid;
        int r = idx >> 4, c = idx & 15;
        npre[q] = *reinterpret_cast<const uint4*>(nfb + (size_t)(row0 + r) * 128 + c * 8);
    }
    // stage H tile (128 x 256 bf16): 4096 uint4, 16 per thread
    #pragma unroll
    for (int q = 0; q < 16; ++q) {
        int idx = q * 256 + tid;
        int r = idx >> 5, c = idx & 31;
        *reinterpret_cast<uint4*>(&Hs[r * P256 + c * 8]) =
            *reinterpret_cast<const uint4*>(H + (size_t)(row0 + r) * 256 + c * 8);
    }
    __syncthreads();

    // ---- phase 1: red = H @ We2t (no activation) ----
    f32x4 acc[4][4] = {};
    #pragma unroll
    for (int ks = 0; ks < 8; ++ks) {
        bf16x8 af[4], bf[4];
        #pragma unroll
        for (int i = 0; i < 4; ++i) {
            int mrow = wm * 64 + i * 16 + (lane & 15);
            af[i] = *reinterpret_cast<const bf16x8*>(&Hs[mrow * P256 + ks * 32 + g8]);
            int nc = wn * 64 + i * 16 + (lane & 15);
            bf[i] = *reinterpret_cast<const bf16x8*>(We2t + (size_t)nc * 256 + ks * 32 + g8);
        }
        #pragma unroll
        for (int i = 0; i < 4; ++i)
            #pragma unroll
            for (int j = 0; j < 4; ++j)
                acc[i][j] = __builtin_amdgcn_mfma_f32_16x16x32_bf16(af[i], bf[j], acc[i][j], 0, 0, 0);
    }
    __syncthreads();   // all Hs reads done -> safe to overlay

    // write Rs (red, bf16) + stage Ns from prefetched registers
    #pragma unroll
    for (int i = 0; i < 4; ++i) {
        int er0 = wm * 64 + i * 16 + ((lane >> 4) << 2);
        #pragma unroll
        for (int j = 0; j < 4; ++j) {
            int fc = wn * 64 + j * 16 + (lane & 15);
            #pragma unroll
            for (int r = 0; r < 4; ++r)
                Rs[(er0 + r) * P128 + fc] = f2bf(acc[i][j][r]);
        }
    }
    #pragma unroll
    for (int q = 0; q < 8; ++q) {
        int idx = q * 256 + tid;
        int r = idx >> 4, c = idx & 15;
        *reinterpret_cast<uint4*>(&Ns[r * P128 + c * 8]) = npre[q];
    }
    __syncthreads();

    // ---- phase 2: hid = lrelu([Ns | Rs] @ Wn1t), 256 out cols ----
    f32x4 a2[2][4][4] = {};
    #pragma unroll
    for (int cb = 0; cb < 2; ++cb) {
        #pragma unroll
        for (int ks = 0; ks < 8; ++ks) {
            bf16x8 af[4], bf[4];
            #pragma unroll
            for (int i = 0; i < 4; ++i) {
                int mrow = wm * 64 + i * 16 + (lane & 15);
                af[i] = (ks < 4)
                    ? *reinterpret_cast<const bf16x8*>(&Ns[mrow * P128 + ks * 32 + g8])
                    : *reinterpret_cast<const bf16x8*>(&Rs[mrow * P128 + (ks - 4) * 32 + g8]);
                int nc = cb * 128 + wn * 64 + i * 16 + (lane & 15);
                bf[i] = *reinterpret_cast<const bf16x8*>(Wn1t + (size_t)nc * 256 + ks * 32 + g8);
            }
            #pragma unroll
            for (int i = 0; i < 4; ++i)
                #pragma unroll
                for (int j = 0; j < 4; ++j)
                    a2[cb][i][j] = __builtin_amdgcn_mfma_f32_16x16x32_bf16(af[i], bf[j], a2[cb][i][j], 0, 0, 0);
        }
    }
    __syncthreads();   // Ns/Rs reads done -> safe to overlay with Hid

    #pragma unroll
    for (int cb = 0; cb < 2; ++cb)
        #pragma unroll
        for (int i = 0; i < 4; ++i) {
            int er0 = wm * 64 + i * 16 + ((lane >> 4) << 2);
            #pragma unroll
            for (int j = 0; j < 4; ++j) {
                int fc = cb * 128 + wn * 64 + j * 16 + (lane & 15);
                #pragma unroll
                for (int r = 0; r < 4; ++r)
                    Hid[(er0 + r) * P256 + fc] = f2bf(lrelu(a2[cb][i][j][r]));
            }
        }
    __syncthreads();

    // ---- phase 3: out = Hid @ Wn2t (fp32, guarded) ----
    f32x4 a3[4][4] = {};
    #pragma unroll
    for (int ks = 0; ks < 8; ++ks) {
        bf16x8 af[4], bf[4];
        #pragma unroll
        for (int i = 0; i < 4; ++i) {
            int mrow = wm * 64 + i * 16 + (lane & 15);
            af[i] = *reinterpret_cast<const bf16x8*>(&Hid[mrow * P256 + ks * 32 + g8]);
            int nc = wn * 64 + i * 16 + (lane & 15);
            bf[i] = *reinterpret_cast<const bf16x8*>(Wn2t + (size_t)nc * 256 + ks * 32 + g8);
        }
        #pragma unroll
        for (int i = 0; i < 4; ++i)
            #pragma unroll
            for (int j = 0; j < 4; ++j)
                a3[i][j] = __builtin_amdgcn_mfma_f32_16x16x32_bf16(af[i], bf[j], a3[i][j], 0, 0, 0);
    }
    #pragma unroll
    for (int i = 0; i < 4; ++i) {
        int gr0 = row0 + wm * 64 + i * 16 + ((lane >> 4) << 2);
        #pragma unroll
        for (int j = 0; j < 4; ++j) {
            int gc = wn * 64 + j * 16 + (lane & 15);
            #pragma unroll
            for (int r = 0; r < 4; ++r) {
                int gr = gr0 + r;
                if (gr < Nreal) out[(size_t)gr * 128 + gc] = a3[i][j][r];
            }
        }
    }
}

// float -> bf16 with zero padding; n_real, n_pad multiples of 4
__global__ __launch_bounds__(256) void cvt_pad(
    const float* __restrict__ x, ushort* __restrict__ y, size_t n_real, size_t n_pad)
{
    size_t i = ((size_t)blockIdx.x * 256 + threadIdx.x) * 4;
    if (i >= n_pad) return;
    ushort4 o;
    if (i < n_real) {
        float4 v = *(const float4*)(x + i);
        o.x = f2bf(v.x); o.y = f2bf(v.y); o.z = f2bf(v.z); o.w = f2bf(v.w);
    } else { o.x = 0; o.y = 0; o.z = 0; o.w = 0; }
    *(ushort4*)(y + i) = o;
}

// transpose + convert all weights to bf16 [N,K] layouts
__global__ __launch_bounds__(256) void wcvt(
    const float* __restrict__ We1, const float* __restrict__ We2,
    const float* __restrict__ Wn1, const float* __restrict__ Wn2,
    ushort* __restrict__ Wabt, ushort* __restrict__ Wet, ushort* __restrict__ We2t,
    ushort* __restrict__ Wn1t, ushort* __restrict__ Wn2t)
{
    int idx = blockIdx.x * 256 + threadIdx.x;
    switch (blockIdx.y) {
    case 0: if (idx < 256*128) { int n = idx >> 7, k = idx & 127; Wabt[idx]            = f2bf(We1[k * 256 + n]); } break;
    case 1: if (idx < 256*128) { int n = idx >> 7, k = idx & 127; Wabt[32768 + idx]    = f2bf(We1[(128 + k) * 256 + n]); } break;
    case 2: if (idx < 256*64)  { int n = idx >> 6, k = idx & 63;  Wet[idx]             = f2bf(We1[(256 + k) * 256 + n]); } break;
    case 3: if (idx < 128*256) { int n = idx >> 8, k = idx & 255; We2t[idx]            = f2bf(We2[k * 128 + n]); } break;
    case 4: if (idx < 256*256) { int n = idx >> 8, k = idx & 255; Wn1t[idx]            = f2bf(Wn1[k * 256 + n]); } break;
    case 5: if (idx < 128*256) { int n = idx >> 8, k = idx & 255; Wn2t[idx]            = f2bf(Wn2[k * 128 + n]); } break;
    }
}

extern "C" void kernel_launch(void* const* d_in, const int* in_sizes, int n_in,
                              void* d_out, int out_size, void* d_ws, size_t ws_size,
                              hipStream_t stream) {
    const float* nf  = (const float*)d_in[0];
    const float* ef  = (const float*)d_in[1];
    const int*   src = (const int*)d_in[2];
    const int*   dst = (const int*)d_in[3];
    const float* We1 = (const float*)d_in[4];
    const float* We2 = (const float*)d_in[5];
    const float* Wn1 = (const float*)d_in[6];
    const float* Wn2 = (const float*)d_in[7];
    float* out = (float*)d_out;

    const int  N  = in_sizes[0] / 128;            // 100000
    const int  E  = in_sizes[2];                  // 500000
    const int  Np = (N + 127) & ~127;             // 100096
    const long Ep = ((long)E + 127) & ~127L;      // 500096

    char* p = (char*)d_ws;
    auto alloc = [&](size_t bytes) { char* r = p; p += (bytes + 255) & ~(size_t)255; return r; };
    ushort* AB   = (ushort*)alloc((size_t)Np * 512 * 2);
    ushort* H    = (ushort*)alloc((size_t)Np * 256 * 2);   // bf16 accumulator
    ushort* nfb  = (ushort*)alloc((size_t)Np * 128 * 2);
    ushort* efb  = (ushort*)alloc((size_t)Ep * 64 * 2);
    ushort* Wabt = (ushort*)alloc(65536 * 2);
    ushort* Wet  = (ushort*)alloc(16384 * 2);
    ushort* We2t = (ushort*)alloc(32768 * 2);
    ushort* Wn1t = (ushort*)alloc(65536 * 2);
    ushort* Wn2t = (ushort*)alloc(32768 * 2);

    dim3 blk(256);

    wcvt<<<dim3(256, 6), blk, 0, stream>>>(We1, We2, Wn1, Wn2, Wabt, Wet, We2t, Wn1t, Wn2t);
    cvt_pad<<<dim3((unsigned)((size_t)Np * 128 / 1024)), blk, 0, stream>>>(nf, nfb, (size_t)N * 128, (size_t)Np * 128);
    cvt_pad<<<dim3((unsigned)((size_t)Ep * 64 / 1024)), blk, 0, stream>>>(ef, efb, (size_t)E * 64, (size_t)Ep * 64);

    // AB = nf @ [We1_s | We1_d]  (single-stage X, in-kernel col loop)
    gemm_ab<<<dim3(Np / 128), blk, 0, stream>>>(nfb, Wabt, AB);

    hipMemsetAsync(H, 0, (size_t)Np * 256 * 2, stream);

    // fused C-GEMM + edge scatter (round-1 verbatim)
    edge_fused<<<dim3((unsigned)(Ep / 128 * 2)), blk, 0, stream>>>(
        efb, Wet, AB, src, dst, H, E);

    // H -> red -> hid -> out in one kernel
    mlp_fused<<<dim3(Np / 128), blk, 0, stream>>>(H, nfb, We2t, Wn1t, Wn2t, out, N);
}